// Round 6
// baseline (107.246 us; speedup 1.0000x reference)
//
#include <hip/hip_runtime.h>
#include <stdint.h>

#define DIM   128
#define MN    1024
#define BATCH 2048
#define ALPHA 0.3f
#define SIGMA 16.0f
#define LOG2E 1.44269504088896f

typedef _Float16 half8 __attribute__((ext_vector_type(8)));
typedef _Float16 half4 __attribute__((ext_vector_type(4)));
typedef float    floatx4 __attribute__((ext_vector_type(4)));

// ws layout (bytes):
//   keys u64[2048]        @ 0        (16 KB)
//   S    f32[1024][128]   @ 16384    (512 KB)
//   cnt  f32[1024]        @ 540672   (4 KB)
//   w2   f32[1024]        @ 544768   (4 KB)
//   wh   f16[1024][128]   @ 548864   (256 KB)
//   wl   f16[1024][128]   @ 811008   (256 KB)
//   xh   f16[2048][128]   @ 1073152  (512 KB)
//   xl   f16[2048][128]   @ 1597440  (512 KB)

// ---------------------------------------------------------------------------
// Kernel 0: prep (one launch): keys=~0, S/cnt=0, w->(wh,wl)+w2, x->(xh,xl).
// hi = f16(v), lo = f16(v - hi): hi+lo carries ~22 mantissa bits => the
// 3-product MFMA dot is fp32-grade.
// ---------------------------------------------------------------------------
__global__ __launch_bounds__(256) void prep_kernel(
    const float* __restrict__ x, const float* __restrict__ w,
    unsigned long long* __restrict__ keys, float4* __restrict__ Sq,
    float* __restrict__ w2,
    _Float16* __restrict__ wh, _Float16* __restrict__ wl,
    _Float16* __restrict__ xh, _Float16* __restrict__ xl)
{
  const int t = threadIdx.x;
  const int bid = blockIdx.x;
  if (bid < 8) {                       // keys = ~0ull (argmin identity)
    keys[bid * 256 + t] = ~0ull;
  } else if (bid < 137) {              // zero S + cnt: 33024 float4
    int i = (bid - 8) * 256 + t;
    Sq[i] = make_float4(0.f, 0.f, 0.f, 0.f);
  } else if (bid < 145) {              // w: 2048 threads, half-row each + w2
    int idx = (bid - 137) * 256 + t;
    int row = idx >> 1, half = idx & 1;
    int base = row * DIM + half * 64;
    float s = 0.f;
#pragma unroll
    for (int q = 0; q < 16; ++q) {
      float4 v = *reinterpret_cast<const float4*>(&w[base + q * 4]);
      s += v.x * v.x + v.y * v.y + v.z * v.z + v.w * v.w;
      half4 h, l;
      h[0] = (_Float16)v.x; l[0] = (_Float16)(v.x - (float)h[0]);
      h[1] = (_Float16)v.y; l[1] = (_Float16)(v.y - (float)h[1]);
      h[2] = (_Float16)v.z; l[2] = (_Float16)(v.z - (float)h[2]);
      h[3] = (_Float16)v.w; l[3] = (_Float16)(v.w - (float)h[3]);
      *reinterpret_cast<half4*>(&wh[base + q * 4]) = h;
      *reinterpret_cast<half4*>(&wl[base + q * 4]) = l;
    }
    s += __shfl_xor(s, 1);
    if (!half) w2[row] = s;
  } else {                             // x: 8192 threads, quarter-row each
    int idx = (bid - 145) * 256 + t;
    int row = idx >> 2, part = idx & 3;
    int base = row * DIM + part * 32;
#pragma unroll
    for (int q = 0; q < 8; ++q) {
      float4 v = *reinterpret_cast<const float4*>(&x[base + q * 4]);
      half4 h, l;
      h[0] = (_Float16)v.x; l[0] = (_Float16)(v.x - (float)h[0]);
      h[1] = (_Float16)v.y; l[1] = (_Float16)(v.y - (float)h[1]);
      h[2] = (_Float16)v.z; l[2] = (_Float16)(v.z - (float)h[2]);
      h[3] = (_Float16)v.w; l[3] = (_Float16)(v.w - (float)h[3]);
      *reinterpret_cast<half4*>(&xh[base + q * 4]) = h;
      *reinterpret_cast<half4*>(&xl[base + q * 4]) = l;
    }
  }
}

// ---------------------------------------------------------------------------
// Kernel 1: BMU via MFMA. 1024 single-wave blocks = 64 u-tiles x 16 b-chunks.
// Wave computes a 16u x 128b score strip: per 16x16 tile, K=128 in 4 chunks,
// 3 split-products (hihi, hilo, lohi; lolo ~2^-22 dropped) into one fp32 acc.
// Fragments are 16B contiguous global loads (A[m=lane&15][k=quad*8+j],
// B[n=lane&15][k=quad*8+j]) -> NO LDS, NO barriers.
// C/D: col(batch)=lane&15, row(unit)=quad*4+reg  [m89/m120 verified layout].
// Score s = |w|^2 - 2 w.x (x^2 drops out of per-b argmin).
// Key = (orderable_bits << 32) | u; shfl-min over quads; atomicMin == argmin.
// ---------------------------------------------------------------------------
__global__ __launch_bounds__(64) void bmu_kernel(
    const _Float16* __restrict__ xh, const _Float16* __restrict__ xl,
    const _Float16* __restrict__ wh, const _Float16* __restrict__ wl,
    const float* __restrict__ w2, unsigned long long* __restrict__ keys)
{
  const int lane = threadIdx.x;
  const int u0 = (blockIdx.x & 63) * 16;
  const int b0 = (blockIdx.x >> 6) * 128;
  const int r  = lane & 15;
  const int q  = lane >> 4;

  half8 Ah[4], Al[4];
  {
    const _Float16* wrh = wh + (u0 + r) * DIM + q * 8;
    const _Float16* wrl = wl + (u0 + r) * DIM + q * 8;
#pragma unroll
    for (int c = 0; c < 4; ++c) {
      Ah[c] = *reinterpret_cast<const half8*>(wrh + c * 32);
      Al[c] = *reinterpret_cast<const half8*>(wrl + c * 32);
    }
  }
  float w2r[4];
#pragma unroll
  for (int i = 0; i < 4; ++i) w2r[i] = w2[u0 + q * 4 + i];

#pragma unroll
  for (int bt = 0; bt < 8; ++bt) {
    const int b = b0 + bt * 16;
    const _Float16* xrh = xh + (b + r) * DIM + q * 8;
    const _Float16* xrl = xl + (b + r) * DIM + q * 8;
    half8 Bh[4], Bl[4];
#pragma unroll
    for (int c = 0; c < 4; ++c) {
      Bh[c] = *reinterpret_cast<const half8*>(xrh + c * 32);
      Bl[c] = *reinterpret_cast<const half8*>(xrl + c * 32);
    }
    floatx4 acc = {0.f, 0.f, 0.f, 0.f};
#pragma unroll
    for (int c = 0; c < 4; ++c) {
      acc = __builtin_amdgcn_mfma_f32_16x16x32_f16(Ah[c], Bh[c], acc, 0, 0, 0);
      acc = __builtin_amdgcn_mfma_f32_16x16x32_f16(Ah[c], Bl[c], acc, 0, 0, 0);
      acc = __builtin_amdgcn_mfma_f32_16x16x32_f16(Al[c], Bh[c], acc, 0, 0, 0);
    }
    unsigned long long kmin = ~0ull;
#pragma unroll
    for (int i = 0; i < 4; ++i) {
      float s = w2r[i] - 2.0f * acc[i];
      unsigned int sb = __float_as_uint(s);
      sb ^= (sb >> 31) ? 0xFFFFFFFFu : 0x80000000u;   // total order
      unsigned long long key =
          ((unsigned long long)sb << 32) | (unsigned int)(u0 + q * 4 + i);
      if (key < kmin) kmin = key;
    }
    unsigned long long o;
    o = __shfl_xor(kmin, 16); if (o < kmin) kmin = o;
    o = __shfl_xor(kmin, 32); if (o < kmin) kmin = o;
    if (lane < 16) atomicMin(&keys[b + r], kmin);
  }
}

// ---------------------------------------------------------------------------
// Kernel 2: scatter. S[v] += x[b], cnt[v] += 1 for v = bmu(b).
// ---------------------------------------------------------------------------
__global__ __launch_bounds__(256) void scatter_kernel(
    const float* __restrict__ x, const unsigned long long* __restrict__ keys,
    float* __restrict__ S, float* __restrict__ cnt)
{
  int idx = blockIdx.x * 256 + threadIdx.x;
  if (idx >= BATCH * 33) return;
  int b  = (int)((unsigned int)idx / 33u);
  int cq = idx - b * 33;
  unsigned int v = (unsigned int)keys[b];
  if (cq < 32) {
    float4 xv = *reinterpret_cast<const float4*>(&x[b * DIM + cq * 4]);
    float* Sv = S + v * DIM + cq * 4;
    unsafeAtomicAdd(&Sv[0], xv.x);
    unsafeAtomicAdd(&Sv[1], xv.y);
    unsafeAtomicAdd(&Sv[2], xv.z);
    unsafeAtomicAdd(&Sv[3], xv.w);
  } else {
    unsafeAtomicAdd(&cnt[v], 1.0f);
  }
}

// ---------------------------------------------------------------------------
// Kernel 3: separable-Gaussian conv + finalize (fused).
// lr[u][v] = alpha * gx(ux-vx) * gy(uy-vy) on the 32x32 meshgrid =>
// delta = Gy (x) ( Gx (x) S ), rowsum likewise from cnt.
// out = w*(1-rowsum) + delta. Block q owns channel quad [4q, 4q+4).
// ---------------------------------------------------------------------------
__global__ __launch_bounds__(256) void convfinal_kernel(
    const float* __restrict__ S, const float* __restrict__ cnt,
    const float* __restrict__ w, const int* __restrict__ itp,
    float* __restrict__ out)
{
  __shared__ float gxt[64], gyt[64];
  __shared__ __align__(16) float T4[1024][4];
  __shared__ float Tc[1024];

  const int t = threadIdx.x;
  const int q = blockIdx.x;

  const float lr_decay = 1.0f - (float)itp[0] * 0.01f;
  const float alpha_op = ALPHA * lr_decay;
  const float sg       = SIGMA * lr_decay;
  const float c2       = -LOG2E / (sg * sg);

  if (t < 63) {
    float dd = (float)(t - 31);
    float g = __builtin_amdgcn_exp2f(c2 * dd * dd);
    gxt[t] = g;
    gyt[t] = alpha_op * g;
  }
  __syncthreads();

#pragma unroll
  for (int r = 0; r < 4; ++r) {
    int p  = t + 256 * r;
    int vy = p >> 5, ux = p & 31;
    float a0 = 0.f, a1 = 0.f, a2 = 0.f, a3 = 0.f, ac = 0.f;
    const float* Srow = S + (vy * 32) * DIM + q * 4;
    const float* Crow = cnt + vy * 32;
#pragma unroll 4
    for (int vx = 0; vx < 32; ++vx) {
      float g = gxt[ux - vx + 31];
      float4 s4 = *reinterpret_cast<const float4*>(&Srow[vx * DIM]);
      a0 = fmaf(g, s4.x, a0); a1 = fmaf(g, s4.y, a1);
      a2 = fmaf(g, s4.z, a2); a3 = fmaf(g, s4.w, a3);
      ac = fmaf(g, Crow[vx], ac);
    }
    T4[p][0] = a0; T4[p][1] = a1; T4[p][2] = a2; T4[p][3] = a3;
    Tc[p] = ac;
  }
  __syncthreads();

#pragma unroll
  for (int r = 0; r < 4; ++r) {
    int p  = t + 256 * r;
    int uy = p >> 5, ux = p & 31;
    float d0 = 0.f, d1 = 0.f, d2 = 0.f, d3 = 0.f, rs = 0.f;
#pragma unroll 4
    for (int vy = 0; vy < 32; ++vy) {
      float g = gyt[uy - vy + 31];
      float4 t4 = *reinterpret_cast<const float4*>(&T4[vy * 32 + ux][0]);
      d0 = fmaf(g, t4.x, d0); d1 = fmaf(g, t4.y, d1);
      d2 = fmaf(g, t4.z, d2); d3 = fmaf(g, t4.w, d3);
      rs = fmaf(g, Tc[vy * 32 + ux], rs);
    }
    float4 wv = *reinterpret_cast<const float4*>(&w[p * DIM + q * 4]);
    float om = 1.0f - rs;
    float4 o;
    o.x = wv.x * om + d0;
    o.y = wv.y * om + d1;
    o.z = wv.z * om + d2;
    o.w = wv.w * om + d3;
    *reinterpret_cast<float4*>(&out[p * DIM + q * 4]) = o;
  }
}

extern "C" void kernel_launch(void* const* d_in, const int* in_sizes, int n_in,
                              void* d_out, int out_size, void* d_ws, size_t ws_size,
                              hipStream_t stream) {
  const float* x   = (const float*)d_in[0];   // [2048,128] f32
  const float* w   = (const float*)d_in[1];   // [1024,128] f32
  const int*   itp = (const int*)d_in[3];     // [1] i32 (meshgrid baked in)
  float* out = (float*)d_out;                 // [1024,128] f32

  char* ws = (char*)d_ws;
  unsigned long long* keys = (unsigned long long*)ws;
  float*     S   = (float*)(ws + 16384);
  float*     cnt = (float*)(ws + 540672);
  float*     w2  = (float*)(ws + 544768);
  _Float16*  wh  = (_Float16*)(ws + 548864);
  _Float16*  wl  = (_Float16*)(ws + 811008);
  _Float16*  xh  = (_Float16*)(ws + 1073152);
  _Float16*  xl  = (_Float16*)(ws + 1597440);

  prep_kernel<<<177, 256, 0, stream>>>(x, w, keys, (float4*)S, w2, wh, wl, xh, xl);
  bmu_kernel<<<1024, 64, 0, stream>>>(xh, xl, wh, wl, w2, keys);
  scatter_kernel<<<(BATCH * 33 + 255) / 256, 256, 0, stream>>>(x, keys, S, cnt);
  convfinal_kernel<<<32, 256, 0, stream>>>(S, cnt, w, itp, out);
}

// Round 7
// 100.264 us; speedup vs baseline: 1.0696x; 1.0696x over previous
//
#include <hip/hip_runtime.h>
#include <stdint.h>

#define DIM   128
#define MN    1024
#define BATCH 2048
#define ALPHA 0.3f
#define SIGMA 16.0f
#define LOG2E 1.44269504088896f

typedef _Float16 half8 __attribute__((ext_vector_type(8)));
typedef _Float16 half4 __attribute__((ext_vector_type(4)));
typedef float    floatx4 __attribute__((ext_vector_type(4)));

// ws layout (bytes):
//   keys u64[2048]        @ 0        (16 KB)
//   S    f32[1024][128]   @ 16384    (512 KB)
//   cnt  f32[1024]        @ 540672   (4 KB)
//   w2   f32[1024]        @ 544768   (4 KB)
//   wh   f16[1024][128]   @ 548864   (256 KB)
//   wl   f16[1024][128]   @ 811008   (256 KB)
//   xh   f16[2048][128]   @ 1073152  (512 KB)
//   xl   f16[2048][128]   @ 1597440  (512 KB)

// ---------------------------------------------------------------------------
// Kernel 0: prep (one launch): keys=~0, S/cnt=0, w->(wh,wl)+w2, x->(xh,xl).
// hi = f16(v), lo = f16(v - hi): hi+lo carries ~22 mantissa bits => the
// 3-product MFMA dot is fp32-grade.
// ---------------------------------------------------------------------------
__global__ __launch_bounds__(256) void prep_kernel(
    const float* __restrict__ x, const float* __restrict__ w,
    unsigned long long* __restrict__ keys, float4* __restrict__ Sq,
    float* __restrict__ w2,
    _Float16* __restrict__ wh, _Float16* __restrict__ wl,
    _Float16* __restrict__ xh, _Float16* __restrict__ xl)
{
  const int t = threadIdx.x;
  const int bid = blockIdx.x;
  if (bid < 8) {                       // keys = ~0ull (argmin identity)
    keys[bid * 256 + t] = ~0ull;
  } else if (bid < 137) {              // zero S + cnt: 33024 float4
    int i = (bid - 8) * 256 + t;
    Sq[i] = make_float4(0.f, 0.f, 0.f, 0.f);
  } else if (bid < 145) {              // w: 2048 threads, half-row each + w2
    int idx = (bid - 137) * 256 + t;
    int row = idx >> 1, half = idx & 1;
    int base = row * DIM + half * 64;
    float s = 0.f;
#pragma unroll
    for (int q = 0; q < 16; ++q) {
      float4 v = *reinterpret_cast<const float4*>(&w[base + q * 4]);
      s += v.x * v.x + v.y * v.y + v.z * v.z + v.w * v.w;
      half4 h, l;
      h[0] = (_Float16)v.x; l[0] = (_Float16)(v.x - (float)h[0]);
      h[1] = (_Float16)v.y; l[1] = (_Float16)(v.y - (float)h[1]);
      h[2] = (_Float16)v.z; l[2] = (_Float16)(v.z - (float)h[2]);
      h[3] = (_Float16)v.w; l[3] = (_Float16)(v.w - (float)h[3]);
      *reinterpret_cast<half4*>(&wh[base + q * 4]) = h;
      *reinterpret_cast<half4*>(&wl[base + q * 4]) = l;
    }
    s += __shfl_xor(s, 1);
    if (!half) w2[row] = s;
  } else {                             // x: 8192 threads, quarter-row each
    int idx = (bid - 145) * 256 + t;
    int row = idx >> 2, part = idx & 3;
    int base = row * DIM + part * 32;
#pragma unroll
    for (int q = 0; q < 8; ++q) {
      float4 v = *reinterpret_cast<const float4*>(&x[base + q * 4]);
      half4 h, l;
      h[0] = (_Float16)v.x; l[0] = (_Float16)(v.x - (float)h[0]);
      h[1] = (_Float16)v.y; l[1] = (_Float16)(v.y - (float)h[1]);
      h[2] = (_Float16)v.z; l[2] = (_Float16)(v.z - (float)h[2]);
      h[3] = (_Float16)v.w; l[3] = (_Float16)(v.w - (float)h[3]);
      *reinterpret_cast<half4*>(&xh[base + q * 4]) = h;
      *reinterpret_cast<half4*>(&xl[base + q * 4]) = l;
    }
  }
}

// ---------------------------------------------------------------------------
// Kernel 1: BMU via MFMA. 256 blocks (16 u-tiles x 16 b-chunks) x 4 waves.
// Wave wv owns the 16-unit sub-tile u0+16*wv, strip of 128 batches.
// Fragments are 16B contiguous global loads (A[m=lane&15][k=quad*8+j],
// B likewise) -> no LDS tiles, no staging barriers. 3-product f16 hi/lo
// split per 32-K chunk (lolo dropped, ~2^-22). unroll 2 caps live B-frags.
// C/D: col(batch)=lane&15, row(unit)=quad*4+reg.
// Keys: per-wave shfl-reduce -> LDS -> 1 atomicMin per batch per block.
// ---------------------------------------------------------------------------
__global__ __launch_bounds__(256) void bmu_kernel(
    const _Float16* __restrict__ xh, const _Float16* __restrict__ xl,
    const _Float16* __restrict__ wh, const _Float16* __restrict__ wl,
    const float* __restrict__ w2, unsigned long long* __restrict__ keys)
{
  __shared__ unsigned long long kb[4][128];   // 4 KB

  const int t    = threadIdx.x;
  const int lane = t & 63;
  const int wv   = t >> 6;
  const int u0   = (blockIdx.x & 15) * 64 + wv * 16;
  const int b0   = (blockIdx.x >> 4) * 128;
  const int r    = lane & 15;
  const int q    = lane >> 4;

  half8 Ah[4], Al[4];
  {
    const _Float16* wrh = wh + (u0 + r) * DIM + q * 8;
    const _Float16* wrl = wl + (u0 + r) * DIM + q * 8;
#pragma unroll
    for (int c = 0; c < 4; ++c) {
      Ah[c] = *reinterpret_cast<const half8*>(wrh + c * 32);
      Al[c] = *reinterpret_cast<const half8*>(wrl + c * 32);
    }
  }
  float w2r[4];
#pragma unroll
  for (int i = 0; i < 4; ++i) w2r[i] = w2[u0 + q * 4 + i];

#pragma unroll 2
  for (int bt = 0; bt < 8; ++bt) {
    const int b = b0 + bt * 16;
    const _Float16* xrh = xh + (b + r) * DIM + q * 8;
    const _Float16* xrl = xl + (b + r) * DIM + q * 8;
    half8 Bh[4], Bl[4];
#pragma unroll
    for (int c = 0; c < 4; ++c) {
      Bh[c] = *reinterpret_cast<const half8*>(xrh + c * 32);
      Bl[c] = *reinterpret_cast<const half8*>(xrl + c * 32);
    }
    floatx4 acc = {0.f, 0.f, 0.f, 0.f};
#pragma unroll
    for (int c = 0; c < 4; ++c) {
      acc = __builtin_amdgcn_mfma_f32_16x16x32_f16(Ah[c], Bh[c], acc, 0, 0, 0);
      acc = __builtin_amdgcn_mfma_f32_16x16x32_f16(Ah[c], Bl[c], acc, 0, 0, 0);
      acc = __builtin_amdgcn_mfma_f32_16x16x32_f16(Al[c], Bh[c], acc, 0, 0, 0);
    }
    unsigned long long kmin = ~0ull;
#pragma unroll
    for (int i = 0; i < 4; ++i) {
      float s = w2r[i] - 2.0f * acc[i];
      unsigned int sb = __float_as_uint(s);
      sb ^= (sb >> 31) ? 0xFFFFFFFFu : 0x80000000u;   // total order
      unsigned long long key =
          ((unsigned long long)sb << 32) | (unsigned int)(u0 + q * 4 + i);
      if (key < kmin) kmin = key;
    }
    unsigned long long o;
    o = __shfl_xor(kmin, 16); if (o < kmin) kmin = o;
    o = __shfl_xor(kmin, 32); if (o < kmin) kmin = o;
    if (lane < 16) kb[wv][bt * 16 + r] = kmin;
  }
  __syncthreads();
  if (t < 128) {
    unsigned long long m = kb[0][t];
    if (kb[1][t] < m) m = kb[1][t];
    if (kb[2][t] < m) m = kb[2][t];
    if (kb[3][t] < m) m = kb[3][t];
    atomicMin(&keys[b0 + t], m);
  }
}

// ---------------------------------------------------------------------------
// Kernel 2: scatter. S[v] += x[b], cnt[v] += 1 for v = bmu(b).
// ---------------------------------------------------------------------------
__global__ __launch_bounds__(256) void scatter_kernel(
    const float* __restrict__ x, const unsigned long long* __restrict__ keys,
    float* __restrict__ S, float* __restrict__ cnt)
{
  int idx = blockIdx.x * 256 + threadIdx.x;
  if (idx >= BATCH * 33) return;
  int b  = (int)((unsigned int)idx / 33u);
  int cq = idx - b * 33;
  unsigned int v = (unsigned int)keys[b];
  if (cq < 32) {
    float4 xv = *reinterpret_cast<const float4*>(&x[b * DIM + cq * 4]);
    float* Sv = S + v * DIM + cq * 4;
    unsafeAtomicAdd(&Sv[0], xv.x);
    unsafeAtomicAdd(&Sv[1], xv.y);
    unsafeAtomicAdd(&Sv[2], xv.z);
    unsafeAtomicAdd(&Sv[3], xv.w);
  } else {
    unsafeAtomicAdd(&cnt[v], 1.0f);
  }
}

// ---------------------------------------------------------------------------
// Kernel 3: separable-Gaussian conv + finalize (fused). 32 blocks x 512 thr.
// lr[u][v] = alpha * gx(ux-vx) * gy(uy-vy) on the 32x32 meshgrid =>
// delta = Gy (x) ( Gx (x) S ), rowsum likewise from cnt.
// out = w*(1-rowsum) + delta. Block q owns channel quad [4q, 4q+4).
// ---------------------------------------------------------------------------
__global__ __launch_bounds__(512) void convfinal_kernel(
    const float* __restrict__ S, const float* __restrict__ cnt,
    const float* __restrict__ w, const int* __restrict__ itp,
    float* __restrict__ out)
{
  __shared__ float gxt[64], gyt[64];
  __shared__ __align__(16) float T4[1024][4];
  __shared__ float Tc[1024];

  const int t = threadIdx.x;
  const int q = blockIdx.x;

  const float lr_decay = 1.0f - (float)itp[0] * 0.01f;
  const float alpha_op = ALPHA * lr_decay;
  const float sg       = SIGMA * lr_decay;
  const float c2       = -LOG2E / (sg * sg);

  if (t < 63) {
    float dd = (float)(t - 31);
    float g = __builtin_amdgcn_exp2f(c2 * dd * dd);
    gxt[t] = g;
    gyt[t] = alpha_op * g;
  }
  __syncthreads();

#pragma unroll
  for (int r = 0; r < 2; ++r) {
    int p  = t + 512 * r;
    int vy = p >> 5, ux = p & 31;
    float a0 = 0.f, a1 = 0.f, a2 = 0.f, a3 = 0.f, ac = 0.f;
    const float* Srow = S + (vy * 32) * DIM + q * 4;
    const float* Crow = cnt + vy * 32;
#pragma unroll 4
    for (int vx = 0; vx < 32; ++vx) {
      float g = gxt[ux - vx + 31];
      float4 s4 = *reinterpret_cast<const float4*>(&Srow[vx * DIM]);
      a0 = fmaf(g, s4.x, a0); a1 = fmaf(g, s4.y, a1);
      a2 = fmaf(g, s4.z, a2); a3 = fmaf(g, s4.w, a3);
      ac = fmaf(g, Crow[vx], ac);
    }
    T4[p][0] = a0; T4[p][1] = a1; T4[p][2] = a2; T4[p][3] = a3;
    Tc[p] = ac;
  }
  __syncthreads();

#pragma unroll
  for (int r = 0; r < 2; ++r) {
    int p  = t + 512 * r;
    int uy = p >> 5, ux = p & 31;
    float d0 = 0.f, d1 = 0.f, d2 = 0.f, d3 = 0.f, rs = 0.f;
#pragma unroll 4
    for (int vy = 0; vy < 32; ++vy) {
      float g = gyt[uy - vy + 31];
      float4 t4 = *reinterpret_cast<const float4*>(&T4[vy * 32 + ux][0]);
      d0 = fmaf(g, t4.x, d0); d1 = fmaf(g, t4.y, d1);
      d2 = fmaf(g, t4.z, d2); d3 = fmaf(g, t4.w, d3);
      rs = fmaf(g, Tc[vy * 32 + ux], rs);
    }
    float4 wv = *reinterpret_cast<const float4*>(&w[p * DIM + q * 4]);
    float om = 1.0f - rs;
    float4 o;
    o.x = wv.x * om + d0;
    o.y = wv.y * om + d1;
    o.z = wv.z * om + d2;
    o.w = wv.w * om + d3;
    *reinterpret_cast<float4*>(&out[p * DIM + q * 4]) = o;
  }
}

extern "C" void kernel_launch(void* const* d_in, const int* in_sizes, int n_in,
                              void* d_out, int out_size, void* d_ws, size_t ws_size,
                              hipStream_t stream) {
  const float* x   = (const float*)d_in[0];   // [2048,128] f32
  const float* w   = (const float*)d_in[1];   // [1024,128] f32
  const int*   itp = (const int*)d_in[3];     // [1] i32 (meshgrid baked in)
  float* out = (float*)d_out;                 // [1024,128] f32

  char* ws = (char*)d_ws;
  unsigned long long* keys = (unsigned long long*)ws;
  float*     S   = (float*)(ws + 16384);
  float*     cnt = (float*)(ws + 540672);
  float*     w2  = (float*)(ws + 544768);
  _Float16*  wh  = (_Float16*)(ws + 548864);
  _Float16*  wl  = (_Float16*)(ws + 811008);
  _Float16*  xh  = (_Float16*)(ws + 1073152);
  _Float16*  xl  = (_Float16*)(ws + 1597440);

  prep_kernel<<<177, 256, 0, stream>>>(x, w, keys, (float4*)S, w2, wh, wl, xh, xl);
  bmu_kernel<<<256, 256, 0, stream>>>(xh, xl, wh, wl, w2, keys);
  scatter_kernel<<<(BATCH * 33 + 255) / 256, 256, 0, stream>>>(x, keys, S, cnt);
  convfinal_kernel<<<32, 512, 0, stream>>>(S, cnt, w, itp, out);
}